// Round 9
// baseline (284.799 us; speedup 1.0000x reference)
//
#include <hip/hip_runtime.h>
#include <cstdint>
#include <cstddef>

// ---------------------------------------------------------------------------
// EdgeAttrGAT forward on MI355X.
// Pipeline: CSR build (deg -> scan -> fill) once per call, then per layer
//   [gemm+att epilogue] -> [agg pass1: softmax + cols 0-63]
//                       -> [agg pass2: cols 64-127]            -> pool -> head.
// All fp32 (threshold 2.4e-5 forbids bf16 MFMA path).
// R1: batch histogram atomics (234us) -> sorted-run boundary detect.
// R2: head_kernel single-block (65us) -> one block per graph.
// R3: agg float4 half-wave gather, 4 loads in flight.
// R4: fillB packed 8B int2 scatter.
// R5: FAILED: 16-edge reg batches regressed agg.
// R6: one node per half-wave. agg pinned ~48.5us across 3 MLP structures,
//     FETCH invariant 146MB @ ~3TB/s -> L2-miss service bound.
// R7: column-split agg (footprint 25.6->12.8MB/pass). FAILED: pass2 read
//     H+32 floats (cols 32-95) instead of H+64 (cols 64-127).
// R8: fix the offset (+64); retest the R7 footprint hypothesis.
// ---------------------------------------------------------------------------

__device__ __forceinline__ float wave_sum(float v) {
#pragma unroll
  for (int m = 32; m >= 1; m >>= 1) v += __shfl_xor(v, m, 64);
  return v;
}

// -------------------- init / CSR build --------------------

__global__ void init_kernel(int* __restrict__ deg, float* __restrict__ gsum,
                            int* __restrict__ gstart, int* __restrict__ gend,
                            int N, int G) {
  int i = blockIdx.x * blockDim.x + threadIdx.x;
  if (i < N) deg[i] = 1;              // self-loop pre-counted
  if (i < G * 128) gsum[i] = 0.f;
  if (i < G) { gstart[i] = 0; gend[i] = 0; }
}

__global__ void count_deg_kernel(const int* __restrict__ edge_index,
                                 int* __restrict__ deg, int E) {
  int e = blockIdx.x * blockDim.x + threadIdx.x;
  if (e < E) atomicAdd(&deg[edge_index[E + e]], 1);   // dst row
}

__global__ void scan1_kernel(const int* __restrict__ deg, int* __restrict__ bsum, int N) {
  __shared__ int ws[4];
  int tid = threadIdx.x;
  int i = blockIdx.x * 256 + tid;
  int v = (i < N) ? deg[i] : 0;
#pragma unroll
  for (int m = 32; m >= 1; m >>= 1) v += __shfl_xor(v, m, 64);
  if ((tid & 63) == 0) ws[tid >> 6] = v;
  __syncthreads();
  if (tid == 0) bsum[blockIdx.x] = ws[0] + ws[1] + ws[2] + ws[3];
}

__device__ __forceinline__ int block_excl_scan_256(int v, int tid, int* wsum) {
  int lane = tid & 63, wid = tid >> 6;
  int incl = v;
#pragma unroll
  for (int off = 1; off < 64; off <<= 1) {
    int t = __shfl_up(incl, off, 64);
    if (lane >= off) incl += t;
  }
  if (lane == 63) wsum[wid] = incl;
  __syncthreads();
  int woff = 0;
#pragma unroll
  for (int w = 0; w < 4; ++w)
    if (w < wid) woff += wsum[w];
  return woff + incl - v;
}

// single block; requires nb <= 256 (N <= 65536)
__global__ void scan2_kernel(const int* __restrict__ bsum, int* __restrict__ boff,
                             int* __restrict__ row_ptr, int nb, int N) {
  __shared__ int wsum[4];
  int tid = threadIdx.x;
  int v = (tid < nb) ? bsum[tid] : 0;
  int excl = block_excl_scan_256(v, tid, wsum);
  if (tid < nb) boff[tid] = excl;
  if (tid == 255) row_ptr[N] = excl + v;   // total (v==0 here)
}

// scan3 + fillA merged: computes row_ptr[i], writes the self-loop entry and
// initializes the atomic cursor in the same pass.
__global__ void scan3_fill_kernel(const int* __restrict__ deg, const int* __restrict__ boff,
                                  int* __restrict__ row_ptr, int2* __restrict__ pk,
                                  int* __restrict__ cur, int N) {
  __shared__ int wsum[4];
  int tid = threadIdx.x;
  int i = blockIdx.x * 256 + tid;
  int v = (i < N) ? deg[i] : 0;
  int excl = block_excl_scan_256(v, tid, wsum);
  if (i < N) {
    int p = boff[blockIdx.x] + excl;
    row_ptr[i] = p;
    pk[p] = make_int2(i, __float_as_int(1.0f));   // self loop
    cur[i] = p + 1;
  }
}

__global__ void fillB_kernel(const int* __restrict__ edge_index, const float* __restrict__ ea,
                             int* __restrict__ cur, int2* __restrict__ pk, int E) {
  int e = blockIdx.x * blockDim.x + threadIdx.x;
  if (e < E) {
    int d0 = edge_index[E + e];
    int s0 = edge_index[e];
    float a0 = ea[e];
    int p = atomicAdd(&cur[d0], 1);
    pk[p] = make_int2(s0, __float_as_int(a0));    // single 8B scatter
  }
}

// -------------------- GEMM (H = X @ W^T) + attention-dot epilogue --------------------
// Block: 64 rows x 128 cols; 256 threads, thread = 4 rows x 8 cols.
// gidx != nullptr => rows gathered from embedding table.

__global__ __launch_bounds__(256) void gemm_att_kernel(
    const float* __restrict__ Xin, const int* __restrict__ gidx,
    const float* __restrict__ W,
    const float* __restrict__ a_src, const float* __restrict__ a_dst,
    float* __restrict__ H, float* __restrict__ sv, float* __restrict__ dv, int N) {
  __shared__ float XsT[32][64];    // [k][row]
  __shared__ float Wt[32][128];    // [k][col]
  __shared__ float av[2][128];

  int tid = threadIdx.x;
  int tx = tid & 15, ty = tid >> 4;
  int rb = blockIdx.x * 64;

  if (tid < 128) { av[0][tid] = a_src[tid]; av[1][tid] = a_dst[tid]; }

  // X staging map: lane-distinct rows (conflict-free LDS transpose writes)
  int r0 = tid & 63;
  int q0 = tid >> 6;                       // 0..3 (and q0+4)
  int gr0 = rb + r0; if (gr0 >= N) gr0 = N - 1;
  const float* rp0 = gidx ? (Xin + (size_t)gidx[gr0] * 128) : (Xin + (size_t)gr0 * 128);

  float acc[4][8];
#pragma unroll
  for (int r = 0; r < 4; ++r)
#pragma unroll
    for (int j = 0; j < 8; ++j) acc[r][j] = 0.f;

#pragma unroll
  for (int ks = 0; ks < 4; ++ks) {
    const int k0 = ks * 32;
    __syncthreads();
    {
      float4 v0 = *(const float4*)(rp0 + k0 + q0 * 4);
      float4 v1 = *(const float4*)(rp0 + k0 + (q0 + 4) * 4);
      XsT[q0 * 4 + 0][r0] = v0.x; XsT[q0 * 4 + 1][r0] = v0.y;
      XsT[q0 * 4 + 2][r0] = v0.z; XsT[q0 * 4 + 3][r0] = v0.w;
      XsT[(q0 + 4) * 4 + 0][r0] = v1.x; XsT[(q0 + 4) * 4 + 1][r0] = v1.y;
      XsT[(q0 + 4) * 4 + 2][r0] = v1.z; XsT[(q0 + 4) * 4 + 3][r0] = v1.w;
    }
#pragma unroll
    for (int it = 0; it < 4; ++it) {
      int idx = tid + it * 256;
      int c = idx & 127, q = idx >> 7;     // q 0..7
      float4 v = *(const float4*)(W + (size_t)c * 128 + k0 + q * 4);
      Wt[q * 4 + 0][c] = v.x; Wt[q * 4 + 1][c] = v.y;
      Wt[q * 4 + 2][c] = v.z; Wt[q * 4 + 3][c] = v.w;
    }
    __syncthreads();
#pragma unroll 8
    for (int k = 0; k < 32; ++k) {
      float4 xa = *(const float4*)&XsT[k][ty * 4];
      float4 wl = *(const float4*)&Wt[k][tx * 4];
      float4 wh = *(const float4*)&Wt[k][tx * 4 + 64];
      float xr[4] = {xa.x, xa.y, xa.z, xa.w};
      float wv[8] = {wl.x, wl.y, wl.z, wl.w, wh.x, wh.y, wh.z, wh.w};
#pragma unroll
      for (int r = 0; r < 4; ++r)
#pragma unroll
        for (int j = 0; j < 8; ++j) acc[r][j] = fmaf(xr[r], wv[j], acc[r][j]);
    }
  }

#pragma unroll
  for (int r = 0; r < 4; ++r) {
    int gr = rb + ty * 4 + r;
    float ps = 0.f, pd = 0.f;
#pragma unroll
    for (int j = 0; j < 4; ++j) {
      ps = fmaf(acc[r][j], av[0][tx * 4 + j], ps);
      ps = fmaf(acc[r][4 + j], av[0][tx * 4 + 64 + j], ps);
      pd = fmaf(acc[r][j], av[1][tx * 4 + j], pd);
      pd = fmaf(acc[r][4 + j], av[1][tx * 4 + 64 + j], pd);
    }
#pragma unroll
    for (int m = 1; m < 16; m <<= 1) {        // reduce across the 16 tx lanes
      ps += __shfl_xor(ps, m, 64);
      pd += __shfl_xor(pd, m, 64);
    }
    if (gr < N) {
      float4 lo = make_float4(acc[r][0], acc[r][1], acc[r][2], acc[r][3]);
      float4 hi = make_float4(acc[r][4], acc[r][5], acc[r][6], acc[r][7]);
      *(float4*)(H + (size_t)gr * 128 + tx * 4) = lo;
      *(float4*)(H + (size_t)gr * 128 + 64 + tx * 4) = hi;
      if (tx == 0) { sv[gr] = ps; dv[gr] = pd; }
    }
  }
}

// -------------------- edge softmax + aggregate, column-split ---------------
// Pass 1 (per node, half-wave): softmax over in-edges; store (src, w_raw)
// to pw and 1/S to invS; gather H[:,0:64] (float2/lane), write X[:,0:64].
// Pass 2: pure weighted gather of H[:,64:128] using pw/invS.

__global__ __launch_bounds__(256) void agg_pass1_kernel(
    const float* __restrict__ H, const float* __restrict__ sv, const float* __restrict__ dv,
    const int* __restrict__ row_ptr, const int2* __restrict__ pk,
    int2* __restrict__ pw, float* __restrict__ invS,
    float* __restrict__ Xout, int N) {
  int tid = threadIdx.x;
  int hw = tid >> 5;              // half-wave id in block: 0..7
  int cl = tid & 31;
  int node = blockIdx.x * 8 + hw;
  if (node >= N) return;
  int p0 = row_ptr[node], p1 = row_ptr[node + 1];
  int deg = p1 - p0;
  float di = dv[node];

  float2 acc = make_float2(0.f, 0.f);
  float S = 0.f;

  if (deg <= 32) {
    float f = -3.4e38f; int sE = 0;
    if (cl < deg) {
      int2 pe = pk[p0 + cl];
      sE = pe.x;
      float t = di + sv[sE];
      t = (t >= 0.f) ? t : 0.2f * t;          // leaky relu
      f = t * __int_as_float(pe.y);
    }
    float m = f;
#pragma unroll
    for (int s = 16; s >= 1; s >>= 1) m = fmaxf(m, __shfl_xor(m, s, 32));
    float w = (cl < deg) ? expf(f - m) : 0.f;
    float Ss = w;
#pragma unroll
    for (int s = 16; s >= 1; s >>= 1) Ss += __shfl_xor(Ss, s, 32);
    S = Ss;
    if (cl < deg) pw[p0 + cl] = make_int2(sE, __float_as_int(w));
    for (int t0 = 0; t0 < deg; t0 += 4) {
      float2 v[4]; float wv[4];
#pragma unroll
      for (int u = 0; u < 4; ++u) {
        int idx = t0 + u;
        float wj = __shfl(w, idx, 32);
        int sj = __shfl(sE, idx, 32);
        bool valid = idx < deg;
        wv[u] = valid ? wj : 0.f;
        const float2* hr = (const float2*)(H + (size_t)(valid ? sj : 0) * 128);
        v[u] = hr[cl];
      }
#pragma unroll
      for (int u = 0; u < 4; ++u) {
        acc.x = fmaf(wv[u], v[u].x, acc.x);
        acc.y = fmaf(wv[u], v[u].y, acc.y);
      }
    }
  } else {
    float m = -3.4e38f;
    for (int p = p0; p < p1; p += 32) {
      int e = p + cl;
      float f = -3.4e38f;
      if (e < p1) {
        int2 pe = pk[e];
        float t = di + sv[pe.x];
        t = (t >= 0.f) ? t : 0.2f * t;
        f = t * __int_as_float(pe.y);
      }
#pragma unroll
      for (int s = 16; s >= 1; s >>= 1) f = fmaxf(f, __shfl_xor(f, s, 32));
      m = fmaxf(m, f);
    }
    for (int p = p0; p < p1; p += 32) {
      int cnt = min(32, p1 - p);
      float w = 0.f; int sE = 0;
      if (cl < cnt) {
        int2 pe = pk[p + cl];
        sE = pe.x;
        float t = di + sv[sE];
        t = (t >= 0.f) ? t : 0.2f * t;
        w = expf(t * __int_as_float(pe.y) - m);
        pw[p + cl] = make_int2(sE, __float_as_int(w));
      }
      float Ss = w;
#pragma unroll
      for (int s = 16; s >= 1; s >>= 1) Ss += __shfl_xor(Ss, s, 32);
      S += Ss;
      for (int t0 = 0; t0 < cnt; t0 += 4) {
        float2 v[4]; float wv[4];
#pragma unroll
        for (int u = 0; u < 4; ++u) {
          int idx = t0 + u;
          float wj = __shfl(w, idx, 32);
          int sj = __shfl(sE, idx, 32);
          bool valid = idx < cnt;
          wv[u] = valid ? wj : 0.f;
          const float2* hr = (const float2*)(H + (size_t)(valid ? sj : 0) * 128);
          v[u] = hr[cl];
        }
#pragma unroll
        for (int u = 0; u < 4; ++u) {
          acc.x = fmaf(wv[u], v[u].x, acc.x);
          acc.y = fmaf(wv[u], v[u].y, acc.y);
        }
      }
    }
  }

  float sc = 1.0f / (S + 1e-16f);
  if (cl == 0) invS[node] = sc;
  float2 o;
  o.x = fmaxf(acc.x * sc, 0.f);           // relu
  o.y = fmaxf(acc.y * sc, 0.f);
  *(float2*)(Xout + (size_t)node * 128 + cl * 2) = o;
}

__global__ __launch_bounds__(256) void agg_pass2_kernel(
    const float* __restrict__ H, const int* __restrict__ row_ptr,
    const int2* __restrict__ pw, const float* __restrict__ invS,
    float* __restrict__ Xout, int N) {
  int tid = threadIdx.x;
  int hw = tid >> 5;
  int cl = tid & 31;
  int node = blockIdx.x * 8 + hw;
  if (node >= N) return;
  int p0 = row_ptr[node], p1 = row_ptr[node + 1];

  float2 acc = make_float2(0.f, 0.f);

  for (int p = p0; p < p1; p += 32) {
    int cnt = min(32, p1 - p);
    float w = 0.f; int sE = 0;
    if (cl < cnt) {
      int2 pe = pw[p + cl];
      sE = pe.x;
      w = __int_as_float(pe.y);
    }
    for (int t0 = 0; t0 < cnt; t0 += 4) {
      float2 v[4]; float wv[4];
#pragma unroll
      for (int u = 0; u < 4; ++u) {
        int idx = t0 + u;
        float wj = __shfl(w, idx, 32);
        int sj = __shfl(sE, idx, 32);
        bool valid = idx < cnt;
        wv[u] = valid ? wj : 0.f;
        // columns 64..127 of row sj (64-FLOAT offset)
        const float2* hr = (const float2*)(H + (size_t)(valid ? sj : 0) * 128 + 64);
        v[u] = hr[cl];
      }
#pragma unroll
      for (int u = 0; u < 4; ++u) {
        acc.x = fmaf(wv[u], v[u].x, acc.x);
        acc.y = fmaf(wv[u], v[u].y, acc.y);
      }
    }
  }

  float sc = invS[node];
  float2 o;
  o.x = fmaxf(acc.x * sc, 0.f);           // relu
  o.y = fmaxf(acc.y * sc, 0.f);
  *(float2*)(Xout + (size_t)node * 128 + 64 + cl * 2) = o;
}

// -------------------- pooling + head --------------------

// batch is SORTED: per-graph counts are run boundaries, no atomics needed.
__global__ void batch_bounds_kernel(const int* __restrict__ batch,
                                    int* __restrict__ gstart, int* __restrict__ gend, int N) {
  int i = blockIdx.x * blockDim.x + threadIdx.x;
  if (i >= N) return;
  int b = batch[i];
  if (i == 0 || batch[i - 1] != b) gstart[b] = i;
  if (i == N - 1 || batch[i + 1] != b) gend[b] = i + 1;
}

__global__ void pool_kernel(const float* __restrict__ X, const int* __restrict__ batch,
                            float* __restrict__ gsum, int N) {
  int col = threadIdx.x & 127;
  int half = threadIdx.x >> 7;
  int base = blockIdx.x * 128;
  int cur = -1; float acc = 0.f;
  for (int j = half; j < 128; j += 2) {
    int n = base + j;
    if (n >= N) break;
    int g = batch[n];
    if (g != cur) {
      if (cur >= 0) atomicAdd(&gsum[cur * 128 + col], acc);
      cur = g; acc = 0.f;
    }
    acc += X[(size_t)n * 128 + col];
  }
  if (cur >= 0) atomicAdd(&gsum[cur * 128 + col], acc);
}

// One block per graph: 4 threads per hidden unit (float4 loads), then one
// wave per output logit. Latency hidden by 64 concurrent blocks.
__global__ __launch_bounds__(256) void head_kernel(
    const float* __restrict__ gsum,
    const int* __restrict__ gstart, const int* __restrict__ gend,
    const float* __restrict__ W3, const float* __restrict__ b3,
    const float* __restrict__ W4, const float* __restrict__ b4,
    float* __restrict__ out, int G) {
  __shared__ float gv[128];
  __shared__ float h[64];
  int gid = blockIdx.x;
  int tid = threadIdx.x;
  float cnt = (float)(gend[gid] - gstart[gid]);
  if (cnt < 1.f) cnt = 1.f;
  if (tid < 128) gv[tid] = gsum[(size_t)gid * 128 + tid] / cnt;
  __syncthreads();
  {
    int c = tid >> 2, part = tid & 3;       // 4 threads per hidden unit
    const float4* w = (const float4*)(W3 + (size_t)c * 128 + part * 32);
    const float4* gg = (const float4*)(gv + part * 32);
    float acc = 0.f;
#pragma unroll
    for (int k = 0; k < 8; ++k) {
      float4 a = gg[k], b = w[k];
      acc = fmaf(a.x, b.x, acc); acc = fmaf(a.y, b.y, acc);
      acc = fmaf(a.z, b.z, acc); acc = fmaf(a.w, b.w, acc);
    }
    acc += __shfl_xor(acc, 1, 64);
    acc += __shfl_xor(acc, 2, 64);
    if (part == 0) { float v = acc + b3[c]; h[c] = (v > 0.f) ? v : 0.f; }
  }
  __syncthreads();
  if (tid < 128) {
    int o = tid >> 6, k = tid & 63;         // wave 0 -> logit 0, wave 1 -> logit 1
    float p = h[k] * W4[o * 64 + k];
    p = wave_sum(p);
    if (k == 0) out[gid * 2 + o] = p + b4[o];
  }
}

// -------------------- launch --------------------

extern "C" void kernel_launch(void* const* d_in, const int* in_sizes, int n_in,
                              void* d_out, int out_size, void* d_ws, size_t ws_size,
                              hipStream_t stream) {
  const int* x_idx = (const int*)d_in[0];
  const int* edge_index = (const int*)d_in[1];
  const float* edge_attr = (const float*)d_in[2];
  const int* batch = (const int*)d_in[3];
  const float* emb = (const float*)d_in[4];
  const float* W1 = (const float*)d_in[5];
  const float* as1 = (const float*)d_in[6];
  const float* ad1 = (const float*)d_in[7];
  const float* W2 = (const float*)d_in[8];
  const float* as2 = (const float*)d_in[9];
  const float* ad2 = (const float*)d_in[10];
  const float* W3 = (const float*)d_in[11];
  const float* b3 = (const float*)d_in[12];
  const float* W4 = (const float*)d_in[13];
  const float* b4 = (const float*)d_in[14];

  const int N = in_sizes[0];
  const int E = in_sizes[2];
  const int G = out_size / 2;
  const int ET = E + N;

  uint8_t* wp = (uint8_t*)d_ws;
  auto take = [&](size_t bytes) -> void* {
    void* p = (void*)wp;
    wp += (bytes + 255) & ~(size_t)255;
    return p;
  };
  float* H    = (float*)take((size_t)N * 128 * 4);
  float* X    = (float*)take((size_t)N * 128 * 4);
  float* sv   = (float*)take((size_t)N * 4);
  float* dv   = (float*)take((size_t)N * 4);
  int*   deg  = (int*)take((size_t)N * 4);
  int*   rowp = (int*)take((size_t)(N + 1) * 4);
  int*   cur  = (int*)take((size_t)N * 4);
  int*   bsum = (int*)take(256 * 4);
  int*   boff = (int*)take(256 * 4);
  int2*  pk   = (int2*)take((size_t)ET * 8);
  int2*  pw   = (int2*)take((size_t)ET * 8);
  float* invS = (float*)take((size_t)N * 4);
  float* gsum = (float*)take((size_t)G * 128 * 4);
  int*   gstart = (int*)take((size_t)G * 4);
  int*   gend   = (int*)take((size_t)G * 4);
  (void)ws_size; (void)n_in;

  const int nb = (N + 255) / 256;   // 196 (<=256 required by scan2)
  const int eb = (E + 255) / 256;

  init_kernel<<<nb, 256, 0, stream>>>(deg, gsum, gstart, gend, N, G);
  count_deg_kernel<<<eb, 256, 0, stream>>>(edge_index, deg, E);
  scan1_kernel<<<nb, 256, 0, stream>>>(deg, bsum, N);
  scan2_kernel<<<1, 256, 0, stream>>>(bsum, boff, rowp, nb, N);
  scan3_fill_kernel<<<nb, 256, 0, stream>>>(deg, boff, rowp, pk, cur, N);
  fillB_kernel<<<eb, 256, 0, stream>>>(edge_index, edge_attr, cur, pk, E);

  const int gb = (N + 63) / 64;
  const int ab = (N + 7) / 8;
  // layer 1 (embedding gather as GEMM input)
  gemm_att_kernel<<<gb, 256, 0, stream>>>(emb, x_idx, W1, as1, ad1, H, sv, dv, N);
  agg_pass1_kernel<<<ab, 256, 0, stream>>>(H, sv, dv, rowp, pk, pw, invS, X, N);
  agg_pass2_kernel<<<ab, 256, 0, stream>>>(H, rowp, pw, invS, X, N);
  // layer 2
  gemm_att_kernel<<<gb, 256, 0, stream>>>(X, nullptr, W2, as2, ad2, H, sv, dv, N);
  agg_pass1_kernel<<<ab, 256, 0, stream>>>(H, sv, dv, rowp, pk, pw, invS, X, N);
  agg_pass2_kernel<<<ab, 256, 0, stream>>>(H, rowp, pw, invS, X, N);
  // pool + head
  batch_bounds_kernel<<<nb, 256, 0, stream>>>(batch, gstart, gend, N);
  pool_kernel<<<(N + 127) / 128, 256, 0, stream>>>(X, batch, gsum, N);
  head_kernel<<<G, 256, 0, stream>>>(gsum, gstart, gend, W3, b3, W4, b4, (float*)d_out, G);
}

// Round 10
// 273.141 us; speedup vs baseline: 1.0427x; 1.0427x over previous
//
#include <hip/hip_runtime.h>
#include <cstdint>
#include <cstddef>

// ---------------------------------------------------------------------------
// EdgeAttrGAT forward on MI355X.
// Pipeline: CSR build (deg -> scan -> fill) once per call, then per layer
//   [gemm+att epilogue] -> [edge softmax aggregate] -> pool -> MLP head.
// All fp32 (threshold 2.4e-5 forbids bf16 MFMA path).
// R1: batch histogram atomics (234us) -> sorted-run boundary detect.
// R2: head_kernel single-block (65us) -> one block per graph.
// R3: agg float4 half-wave gather, 4 loads in flight.
// R4: fillB packed 8B int2 scatter.
// R5: FAILED: 16-edge reg batches regressed agg.
// R6: one node per half-wave; agg pinned ~48.5us -> L2-miss service bound.
// R7/R8: column-split agg net-negative (284.8 vs 276.6) -> reverted.
// R9: CSR build was the top cost (fillB 44us, WRITE 39MB for 5.2MB payload:
//     8B scatters + cur atomics ping-pong lines across 8 non-coherent XCD
//     L2s). Partition count_deg/fillB by dst range with r=blockIdx&7 (round-
//     robin block->XCD) so every written/atomic line is single-XCD; edge
//     list is re-read ~8x but read-only lines replicate in L2 for free.
// ---------------------------------------------------------------------------

#define CSR_CHUNK 8192
#define NXCD 8

__device__ __forceinline__ float wave_sum(float v) {
#pragma unroll
  for (int m = 32; m >= 1; m >>= 1) v += __shfl_xor(v, m, 64);
  return v;
}

// -------------------- init / CSR build --------------------

__global__ void init_kernel(int* __restrict__ deg, float* __restrict__ gsum,
                            int* __restrict__ gstart, int* __restrict__ gend,
                            int N, int G) {
  int i = blockIdx.x * blockDim.x + threadIdx.x;
  if (i < N) deg[i] = 1;              // self-loop pre-counted
  if (i < G * 128) gsum[i] = 0.f;
  if (i < G) { gstart[i] = 0; gend[i] = 0; }
}

// Partitioned degree count: block (r,s) scans edge chunk s, keeps dst in
// range r. All atomic target lines for range r stay on one XCD's L2.
__global__ void count_deg_part_kernel(const int* __restrict__ edge_index,
                                      int* __restrict__ deg, int E, int RN) {
  int r = blockIdx.x & (NXCD - 1);
  int s = blockIdx.x >> 3;
  int lo = r * RN, hi = lo + RN;
  int e1 = min(E, (s + 1) * CSR_CHUNK);
  for (int e = s * CSR_CHUNK + threadIdx.x; e < e1; e += blockDim.x) {
    int d = edge_index[E + e];
    if (d >= lo && d < hi) atomicAdd(&deg[d], 1);
  }
}

__global__ void scan1_kernel(const int* __restrict__ deg, int* __restrict__ bsum, int N) {
  __shared__ int ws[4];
  int tid = threadIdx.x;
  int i = blockIdx.x * 256 + tid;
  int v = (i < N) ? deg[i] : 0;
#pragma unroll
  for (int m = 32; m >= 1; m >>= 1) v += __shfl_xor(v, m, 64);
  if ((tid & 63) == 0) ws[tid >> 6] = v;
  __syncthreads();
  if (tid == 0) bsum[blockIdx.x] = ws[0] + ws[1] + ws[2] + ws[3];
}

__device__ __forceinline__ int block_excl_scan_256(int v, int tid, int* wsum) {
  int lane = tid & 63, wid = tid >> 6;
  int incl = v;
#pragma unroll
  for (int off = 1; off < 64; off <<= 1) {
    int t = __shfl_up(incl, off, 64);
    if (lane >= off) incl += t;
  }
  if (lane == 63) wsum[wid] = incl;
  __syncthreads();
  int woff = 0;
#pragma unroll
  for (int w = 0; w < 4; ++w)
    if (w < wid) woff += wsum[w];
  return woff + incl - v;
}

// single block; requires nb <= 256 (N <= 65536)
__global__ void scan2_kernel(const int* __restrict__ bsum, int* __restrict__ boff,
                             int* __restrict__ row_ptr, int nb, int N) {
  __shared__ int wsum[4];
  int tid = threadIdx.x;
  int v = (tid < nb) ? bsum[tid] : 0;
  int excl = block_excl_scan_256(v, tid, wsum);
  if (tid < nb) boff[tid] = excl;
  if (tid == 255) row_ptr[N] = excl + v;   // total (v==0 here)
}

// scan3 + fillA merged: computes row_ptr[i], writes the self-loop entry and
// initializes the atomic cursor in the same pass.
__global__ void scan3_fill_kernel(const int* __restrict__ deg, const int* __restrict__ boff,
                                  int* __restrict__ row_ptr, int2* __restrict__ pk,
                                  int* __restrict__ cur, int N) {
  __shared__ int wsum[4];
  int tid = threadIdx.x;
  int i = blockIdx.x * 256 + tid;
  int v = (i < N) ? deg[i] : 0;
  int excl = block_excl_scan_256(v, tid, wsum);
  if (i < N) {
    int p = boff[blockIdx.x] + excl;
    row_ptr[i] = p;
    pk[p] = make_int2(i, __float_as_int(1.0f));   // self loop
    cur[i] = p + 1;
  }
}

// Partitioned CSR fill: same (r,s) decomposition; cur atomics and pk stores
// for range r issue only from XCD r -> no cross-XCD line migration.
__global__ void fillB_part_kernel(const int* __restrict__ edge_index,
                                  const float* __restrict__ ea,
                                  int* __restrict__ cur, int2* __restrict__ pk,
                                  int E, int RN) {
  int r = blockIdx.x & (NXCD - 1);
  int s = blockIdx.x >> 3;
  int lo = r * RN, hi = lo + RN;
  int e1 = min(E, (s + 1) * CSR_CHUNK);
  for (int e = s * CSR_CHUNK + threadIdx.x; e < e1; e += blockDim.x) {
    int d = edge_index[E + e];
    if (d >= lo && d < hi) {
      int s0 = edge_index[e];
      float a0 = ea[e];
      int p = atomicAdd(&cur[d], 1);
      pk[p] = make_int2(s0, __float_as_int(a0));
    }
  }
}

// -------------------- GEMM (H = X @ W^T) + attention-dot epilogue --------------------
// Block: 64 rows x 128 cols; 256 threads, thread = 4 rows x 8 cols.
// gidx != nullptr => rows gathered from embedding table.

__global__ __launch_bounds__(256) void gemm_att_kernel(
    const float* __restrict__ Xin, const int* __restrict__ gidx,
    const float* __restrict__ W,
    const float* __restrict__ a_src, const float* __restrict__ a_dst,
    float* __restrict__ H, float* __restrict__ sv, float* __restrict__ dv, int N) {
  __shared__ float XsT[32][64];    // [k][row]
  __shared__ float Wt[32][128];    // [k][col]
  __shared__ float av[2][128];

  int tid = threadIdx.x;
  int tx = tid & 15, ty = tid >> 4;
  int rb = blockIdx.x * 64;

  if (tid < 128) { av[0][tid] = a_src[tid]; av[1][tid] = a_dst[tid]; }

  // X staging map: lane-distinct rows (conflict-free LDS transpose writes)
  int r0 = tid & 63;
  int q0 = tid >> 6;                       // 0..3 (and q0+4)
  int gr0 = rb + r0; if (gr0 >= N) gr0 = N - 1;
  const float* rp0 = gidx ? (Xin + (size_t)gidx[gr0] * 128) : (Xin + (size_t)gr0 * 128);

  float acc[4][8];
#pragma unroll
  for (int r = 0; r < 4; ++r)
#pragma unroll
    for (int j = 0; j < 8; ++j) acc[r][j] = 0.f;

#pragma unroll
  for (int ks = 0; ks < 4; ++ks) {
    const int k0 = ks * 32;
    __syncthreads();
    {
      float4 v0 = *(const float4*)(rp0 + k0 + q0 * 4);
      float4 v1 = *(const float4*)(rp0 + k0 + (q0 + 4) * 4);
      XsT[q0 * 4 + 0][r0] = v0.x; XsT[q0 * 4 + 1][r0] = v0.y;
      XsT[q0 * 4 + 2][r0] = v0.z; XsT[q0 * 4 + 3][r0] = v0.w;
      XsT[(q0 + 4) * 4 + 0][r0] = v1.x; XsT[(q0 + 4) * 4 + 1][r0] = v1.y;
      XsT[(q0 + 4) * 4 + 2][r0] = v1.z; XsT[(q0 + 4) * 4 + 3][r0] = v1.w;
    }
#pragma unroll
    for (int it = 0; it < 4; ++it) {
      int idx = tid + it * 256;
      int c = idx & 127, q = idx >> 7;     // q 0..7
      float4 v = *(const float4*)(W + (size_t)c * 128 + k0 + q * 4);
      Wt[q * 4 + 0][c] = v.x; Wt[q * 4 + 1][c] = v.y;
      Wt[q * 4 + 2][c] = v.z; Wt[q * 4 + 3][c] = v.w;
    }
    __syncthreads();
#pragma unroll 8
    for (int k = 0; k < 32; ++k) {
      float4 xa = *(const float4*)&XsT[k][ty * 4];
      float4 wl = *(const float4*)&Wt[k][tx * 4];
      float4 wh = *(const float4*)&Wt[k][tx * 4 + 64];
      float xr[4] = {xa.x, xa.y, xa.z, xa.w};
      float wv[8] = {wl.x, wl.y, wl.z, wl.w, wh.x, wh.y, wh.z, wh.w};
#pragma unroll
      for (int r = 0; r < 4; ++r)
#pragma unroll
        for (int j = 0; j < 8; ++j) acc[r][j] = fmaf(xr[r], wv[j], acc[r][j]);
    }
  }

#pragma unroll
  for (int r = 0; r < 4; ++r) {
    int gr = rb + ty * 4 + r;
    float ps = 0.f, pd = 0.f;
#pragma unroll
    for (int j = 0; j < 4; ++j) {
      ps = fmaf(acc[r][j], av[0][tx * 4 + j], ps);
      ps = fmaf(acc[r][4 + j], av[0][tx * 4 + 64 + j], ps);
      pd = fmaf(acc[r][j], av[1][tx * 4 + j], pd);
      pd = fmaf(acc[r][4 + j], av[1][tx * 4 + 64 + j], pd);
    }
#pragma unroll
    for (int m = 1; m < 16; m <<= 1) {        // reduce across the 16 tx lanes
      ps += __shfl_xor(ps, m, 64);
      pd += __shfl_xor(pd, m, 64);
    }
    if (gr < N) {
      float4 lo = make_float4(acc[r][0], acc[r][1], acc[r][2], acc[r][3]);
      float4 hi = make_float4(acc[r][4], acc[r][5], acc[r][6], acc[r][7]);
      *(float4*)(H + (size_t)gr * 128 + tx * 4) = lo;
      *(float4*)(H + (size_t)gr * 128 + 64 + tx * 4) = hi;
      if (tx == 0) { sv[gr] = ps; dv[gr] = pd; }
    }
  }
}

// -------------------- edge softmax + aggregate (one node per HALF-WAVE) ----
// 32 lanes own one node: width-32 softmax reductions; gather = one 512B
// H row per float4 load (32 lanes x 16B), 4 loads in flight per half-wave.

__global__ __launch_bounds__(256) void agg_kernel(
    const float* __restrict__ H, const float* __restrict__ sv, const float* __restrict__ dv,
    const int* __restrict__ row_ptr, const int2* __restrict__ pk,
    float* __restrict__ Xout, int N) {
  int tid = threadIdx.x;
  int hw = tid >> 5;              // half-wave id in block: 0..7
  int cl = tid & 31;
  int node = blockIdx.x * 8 + hw;
  if (node >= N) return;
  int p0 = row_ptr[node], p1 = row_ptr[node + 1];
  int deg = p1 - p0;
  float di = dv[node];

  float4 acc = make_float4(0.f, 0.f, 0.f, 0.f);
  float S = 0.f;

  if (deg <= 32) {
    // fast path: logits stay in registers, single sv gather
    float f = -3.4e38f; int sE = 0;
    if (cl < deg) {
      int2 pe = pk[p0 + cl];
      sE = pe.x;
      float t = di + sv[sE];
      t = (t >= 0.f) ? t : 0.2f * t;          // leaky relu
      f = t * __int_as_float(pe.y);
    }
    float m = f;
#pragma unroll
    for (int s = 16; s >= 1; s >>= 1) m = fmaxf(m, __shfl_xor(m, s, 32));
    float w = (cl < deg) ? expf(f - m) : 0.f;
    float Ss = w;
#pragma unroll
    for (int s = 16; s >= 1; s >>= 1) Ss += __shfl_xor(Ss, s, 32);
    S = Ss;
    for (int t0 = 0; t0 < deg; t0 += 4) {
      float4 v[4]; float wv[4];
#pragma unroll
      for (int u = 0; u < 4; ++u) {
        int idx = t0 + u;
        float wj = __shfl(w, idx, 32);
        int sj = __shfl(sE, idx, 32);
        bool valid = idx < deg;
        wv[u] = valid ? wj : 0.f;
        const float4* hr = (const float4*)(H + (size_t)(valid ? sj : 0) * 128);
        v[u] = hr[cl];
      }
#pragma unroll
      for (int u = 0; u < 4; ++u) {
        acc.x = fmaf(wv[u], v[u].x, acc.x);
        acc.y = fmaf(wv[u], v[u].y, acc.y);
        acc.z = fmaf(wv[u], v[u].z, acc.z);
        acc.w = fmaf(wv[u], v[u].w, acc.w);
      }
    }
  } else {
    // general chunked path (deg > 32, rarer)
    float m = -3.4e38f;
    for (int p = p0; p < p1; p += 32) {
      int e = p + cl;
      float f = -3.4e38f;
      if (e < p1) {
        int2 pe = pk[e];
        float t = di + sv[pe.x];
        t = (t >= 0.f) ? t : 0.2f * t;
        f = t * __int_as_float(pe.y);
      }
#pragma unroll
      for (int s = 16; s >= 1; s >>= 1) f = fmaxf(f, __shfl_xor(f, s, 32));
      m = fmaxf(m, f);
    }
    for (int p = p0; p < p1; p += 32) {
      int cnt = min(32, p1 - p);
      float w = 0.f; int sE = 0;
      if (cl < cnt) {
        int2 pe = pk[p + cl];
        sE = pe.x;
        float t = di + sv[sE];
        t = (t >= 0.f) ? t : 0.2f * t;
        w = expf(t * __int_as_float(pe.y) - m);
      }
      float Ss = w;
#pragma unroll
      for (int s = 16; s >= 1; s >>= 1) Ss += __shfl_xor(Ss, s, 32);
      S += Ss;
      for (int t0 = 0; t0 < cnt; t0 += 4) {
        float4 v[4]; float wv[4];
#pragma unroll
        for (int u = 0; u < 4; ++u) {
          int idx = t0 + u;
          float wj = __shfl(w, idx, 32);
          int sj = __shfl(sE, idx, 32);
          bool valid = idx < cnt;
          wv[u] = valid ? wj : 0.f;
          const float4* hr = (const float4*)(H + (size_t)(valid ? sj : 0) * 128);
          v[u] = hr[cl];
        }
#pragma unroll
        for (int u = 0; u < 4; ++u) {
          acc.x = fmaf(wv[u], v[u].x, acc.x);
          acc.y = fmaf(wv[u], v[u].y, acc.y);
          acc.z = fmaf(wv[u], v[u].z, acc.z);
          acc.w = fmaf(wv[u], v[u].w, acc.w);
        }
      }
    }
  }

  float sc = 1.0f / (S + 1e-16f);
  float4 o;
  o.x = fmaxf(acc.x * sc, 0.f);           // relu
  o.y = fmaxf(acc.y * sc, 0.f);
  o.z = fmaxf(acc.z * sc, 0.f);
  o.w = fmaxf(acc.w * sc, 0.f);
  *(float4*)(Xout + (size_t)node * 128 + cl * 4) = o;
}

// -------------------- pooling + head --------------------

// batch is SORTED: per-graph counts are run boundaries, no atomics needed.
__global__ void batch_bounds_kernel(const int* __restrict__ batch,
                                    int* __restrict__ gstart, int* __restrict__ gend, int N) {
  int i = blockIdx.x * blockDim.x + threadIdx.x;
  if (i >= N) return;
  int b = batch[i];
  if (i == 0 || batch[i - 1] != b) gstart[b] = i;
  if (i == N - 1 || batch[i + 1] != b) gend[b] = i + 1;
}

__global__ void pool_kernel(const float* __restrict__ X, const int* __restrict__ batch,
                            float* __restrict__ gsum, int N) {
  int col = threadIdx.x & 127;
  int half = threadIdx.x >> 7;
  int base = blockIdx.x * 128;
  int cur = -1; float acc = 0.f;
  for (int j = half; j < 128; j += 2) {
    int n = base + j;
    if (n >= N) break;
    int g = batch[n];
    if (g != cur) {
      if (cur >= 0) atomicAdd(&gsum[cur * 128 + col], acc);
      cur = g; acc = 0.f;
    }
    acc += X[(size_t)n * 128 + col];
  }
  if (cur >= 0) atomicAdd(&gsum[cur * 128 + col], acc);
}

// One block per graph: 4 threads per hidden unit (float4 loads), then one
// wave per output logit. Latency hidden by 64 concurrent blocks.
__global__ __launch_bounds__(256) void head_kernel(
    const float* __restrict__ gsum,
    const int* __restrict__ gstart, const int* __restrict__ gend,
    const float* __restrict__ W3, const float* __restrict__ b3,
    const float* __restrict__ W4, const float* __restrict__ b4,
    float* __restrict__ out, int G) {
  __shared__ float gv[128];
  __shared__ float h[64];
  int gid = blockIdx.x;
  int tid = threadIdx.x;
  float cnt = (float)(gend[gid] - gstart[gid]);
  if (cnt < 1.f) cnt = 1.f;
  if (tid < 128) gv[tid] = gsum[(size_t)gid * 128 + tid] / cnt;
  __syncthreads();
  {
    int c = tid >> 2, part = tid & 3;       // 4 threads per hidden unit
    const float4* w = (const float4*)(W3 + (size_t)c * 128 + part * 32);
    const float4* gg = (const float4*)(gv + part * 32);
    float acc = 0.f;
#pragma unroll
    for (int k = 0; k < 8; ++k) {
      float4 a = gg[k], b = w[k];
      acc = fmaf(a.x, b.x, acc); acc = fmaf(a.y, b.y, acc);
      acc = fmaf(a.z, b.z, acc); acc = fmaf(a.w, b.w, acc);
    }
    acc += __shfl_xor(acc, 1, 64);
    acc += __shfl_xor(acc, 2, 64);
    if (part == 0) { float v = acc + b3[c]; h[c] = (v > 0.f) ? v : 0.f; }
  }
  __syncthreads();
  if (tid < 128) {
    int o = tid >> 6, k = tid & 63;         // wave 0 -> logit 0, wave 1 -> logit 1
    float p = h[k] * W4[o * 64 + k];
    p = wave_sum(p);
    if (k == 0) out[gid * 2 + o] = p + b4[o];
  }
}

// -------------------- launch --------------------

extern "C" void kernel_launch(void* const* d_in, const int* in_sizes, int n_in,
                              void* d_out, int out_size, void* d_ws, size_t ws_size,
                              hipStream_t stream) {
  const int* x_idx = (const int*)d_in[0];
  const int* edge_index = (const int*)d_in[1];
  const float* edge_attr = (const float*)d_in[2];
  const int* batch = (const int*)d_in[3];
  const float* emb = (const float*)d_in[4];
  const float* W1 = (const float*)d_in[5];
  const float* as1 = (const float*)d_in[6];
  const float* ad1 = (const float*)d_in[7];
  const float* W2 = (const float*)d_in[8];
  const float* as2 = (const float*)d_in[9];
  const float* ad2 = (const float*)d_in[10];
  const float* W3 = (const float*)d_in[11];
  const float* b3 = (const float*)d_in[12];
  const float* W4 = (const float*)d_in[13];
  const float* b4 = (const float*)d_in[14];

  const int N = in_sizes[0];
  const int E = in_sizes[2];
  const int G = out_size / 2;
  const int ET = E + N;

  uint8_t* wp = (uint8_t*)d_ws;
  auto take = [&](size_t bytes) -> void* {
    void* p = (void*)wp;
    wp += (bytes + 255) & ~(size_t)255;
    return p;
  };
  float* H    = (float*)take((size_t)N * 128 * 4);
  float* X    = (float*)take((size_t)N * 128 * 4);
  float* sv   = (float*)take((size_t)N * 4);
  float* dv   = (float*)take((size_t)N * 4);
  int*   deg  = (int*)take((size_t)N * 4);
  int*   rowp = (int*)take((size_t)(N + 1) * 4);
  int*   cur  = (int*)take((size_t)N * 4);
  int*   bsum = (int*)take(256 * 4);
  int*   boff = (int*)take(256 * 4);
  int2*  pk   = (int2*)take((size_t)ET * 8);
  float* gsum = (float*)take((size_t)G * 128 * 4);
  int*   gstart = (int*)take((size_t)G * 4);
  int*   gend   = (int*)take((size_t)G * 4);
  (void)ws_size; (void)n_in;

  const int nb = (N + 255) / 256;   // 196 (<=256 required by scan2)
  const int RN = (N + NXCD - 1) / NXCD;           // dst range per XCD
  const int ns = (E + CSR_CHUNK - 1) / CSR_CHUNK; // edge slices
  const int pb = ns * NXCD;                       // partitioned grid

  init_kernel<<<nb, 256, 0, stream>>>(deg, gsum, gstart, gend, N, G);
  count_deg_part_kernel<<<pb, 256, 0, stream>>>(edge_index, deg, E, RN);
  scan1_kernel<<<nb, 256, 0, stream>>>(deg, bsum, N);
  scan2_kernel<<<1, 256, 0, stream>>>(bsum, boff, rowp, nb, N);
  scan3_fill_kernel<<<nb, 256, 0, stream>>>(deg, boff, rowp, pk, cur, N);
  fillB_part_kernel<<<pb, 256, 0, stream>>>(edge_index, edge_attr, cur, pk, E, RN);

  const int gb = (N + 63) / 64;
  const int ab = (N + 7) / 8;
  // layer 1 (embedding gather as GEMM input)
  gemm_att_kernel<<<gb, 256, 0, stream>>>(emb, x_idx, W1, as1, ad1, H, sv, dv, N);
  agg_kernel<<<ab, 256, 0, stream>>>(H, sv, dv, rowp, pk, X, N);
  // layer 2
  gemm_att_kernel<<<gb, 256, 0, stream>>>(X, nullptr, W2, as2, ad2, H, sv, dv, N);
  agg_kernel<<<ab, 256, 0, stream>>>(H, sv, dv, rowp, pk, X, N);
  // pool + head
  batch_bounds_kernel<<<nb, 256, 0, stream>>>(batch, gstart, gend, N);
  pool_kernel<<<(N + 127) / 128, 256, 0, stream>>>(X, batch, gsum, N);
  head_kernel<<<G, 256, 0, stream>>>(gsum, gstart, gend, W3, b3, W4, b4, (float*)d_out, G);
}